// Round 3
// baseline (145.247 us; speedup 1.0000x reference)
//
#include <hip/hip_runtime.h>
#include <hip/hip_cooperative_groups.h>

namespace cg = cooperative_groups;

#define HW    16384   // 128*128
#define BD    16
#define NB    32
#define TAUC  100.0f

// ws float layout:
//   A   : [0, 32*HW)              gathered planes cat[i,:,:,0] (i<16: x2, i>=16: x1)
//   PD2 : [32*HW, 32*HW+1024)     sum_k (y_i - a_j)^2   (atomic accumulated)
//   US2 : [32*HW+1024, +256)      sum_k (u8_i - u9_j)^2 (atomic accumulated)
#define A_OFF   0
#define PD_OFF  (32*HW)
#define US_OFF  (32*HW + 1024)

__device__ __forceinline__ float wave_sum(float v) {
    for (int off = 32; off > 0; off >>= 1) v += __shfl_down(v, off, 64);
    return v;
}
__device__ __forceinline__ float wave_min(float v) {
    for (int off = 32; off > 0; off >>= 1) v = fminf(v, __shfl_down(v, off, 64));
    return v;
}

union SmemU {
    struct { float sA[32][66]; float sY[32][66]; } pd;   // 16.9 KB
    struct { float s8[16][130]; float s9[16][130]; } us; // 16.6 KB
};

__global__ __launch_bounds__(256)
void k_fused(const float* __restrict__ x1, const float* __restrict__ x2,
             const float* __restrict__ vs, const float* __restrict__ u,
             const float* __restrict__ dtp, const float* __restrict__ dxp,
             float* __restrict__ ws, float* __restrict__ outp)
{
    cg::grid_group grid = cg::this_grid();
    int tid = threadIdx.x, blk = blockIdx.x;
    __shared__ SmemU sm;
    __shared__ float sc0[32], scx[32], scy[32], sdt[32];
    __shared__ float rp[4], ro[4], rm[4];

    float* A = ws + A_OFF;

    // ---------------- phase 1: gather A (21 MB strided HBM) ----------------
    {
        int base = blk * 2048;
#pragma unroll
        for (int s = 0; s < 8; ++s) {
            int e = base + s * 256 + tid;
            int i = e >> 14, p = e & (HW - 1);
            const float* src = (i < BD) ? x2 : x1;
            int b = i & (BD - 1);
            A[e] = src[(size_t)((b << 14) + p) * 10];
        }
        if (blk == 0) {
            for (int q = tid; q < 1280; q += 256) ws[PD_OFF + q] = 0.0f;
        }
    }
    __threadfence();
    grid.sync();
    __threadfence();

    // ---------------- phase 2 ----------------
    if (blk < 128) {
        // PD chunk: k-range [blk*128, blk*128+128)
        if (tid < 32) {
            int b = tid & 15;
            sc0[tid] = vs[b * 3 + 0];
            scx[tid] = vs[b * 3 + 1];
            scy[tid] = vs[b * 3 + 2];
            sdt[tid] = dtp[b];
        }
        float dxv = dxp[0];
        float inv_dx = 1.0f / dxv, inv_dx2 = inv_dx * inv_dx;
        __syncthreads();
        int k0 = blk * 128;
        float a00 = 0.f, a01 = 0.f, a10 = 0.f, a11 = 0.f;
        int ti = tid >> 4, tj = tid & 15;
        for (int sub = 0; sub < 2; ++sub) {
            int kb = k0 + sub * 64;
            for (int e = tid; e < 2048; e += 256) {
                int row = e >> 6, kk = e & 63;
                int p = kb + kk;
                int h = p >> 7, w = p & 127;
                const float* a = A + row * HW;
                float c   = a[p];
                float aw1 = a[(h << 7) | ((w + 1) & 127)];
                float awm = a[(h << 7) | ((w - 1) & 127)];
                float ah1 = a[(((h + 1) & 127) << 7) | w];
                float ahm = a[(((h - 1) & 127) << 7) | w];
                float lap = aw1 + awm + ah1 + ahm - 4.0f * c;
                float cx = scx[row], cy = scy[row];
                float xt = (cx <= 0.0f) ? (-cx * (c - aw1)) : (cx * (c - awm));
                float yt = (cy >= 0.0f) ? ( cy * (c - ahm)) : (-cy * (c - ah1));
                float yv = c - sdt[row] * (c * (xt + yt)) * inv_dx
                             + sc0[row] * lap * inv_dx2;
                sm.pd.sA[row][kk] = c;
                sm.pd.sY[row][kk] = yv;
            }
            __syncthreads();
#pragma unroll 4
            for (int kk = 0; kk < 64; kk += 2) {
                float2 y0 = *reinterpret_cast<const float2*>(&sm.pd.sY[ti][kk]);
                float2 y1 = *reinterpret_cast<const float2*>(&sm.pd.sY[ti + 16][kk]);
                float2 b0 = *reinterpret_cast<const float2*>(&sm.pd.sA[tj][kk]);
                float2 b1 = *reinterpret_cast<const float2*>(&sm.pd.sA[tj + 16][kk]);
                float d;
                d = y0.x - b0.x; a00 += d * d;
                d = y0.y - b0.y; a00 += d * d;
                d = y0.x - b1.x; a01 += d * d;
                d = y0.y - b1.y; a01 += d * d;
                d = y1.x - b0.x; a10 += d * d;
                d = y1.y - b0.y; a10 += d * d;
                d = y1.x - b1.x; a11 += d * d;
                d = y1.y - b1.y; a11 += d * d;
            }
            __syncthreads();
        }
        float* PD2 = ws + PD_OFF;
        atomicAdd(&PD2[ti * 32 + tj],              a00);
        atomicAdd(&PD2[ti * 32 + tj + 16],         a01);
        atomicAdd(&PD2[(ti + 16) * 32 + tj],       a10);
        atomicAdd(&PD2[(ti + 16) * 32 + tj + 16],  a11);
    } else {
        // US chunk: k-range [(blk-128)*128, +128), read u strided directly
        int c = blk - 128, k0 = c * 128;
#pragma unroll
        for (int s = 0; s < 8; ++s) {
            int e = s * 256 + tid;
            int row = e >> 7, kk = e & 127;
            float2 v = *reinterpret_cast<const float2*>(
                u + (size_t)((row << 14) + k0 + kk) * 10 + 8);
            sm.us.s8[row][kk] = v.x;
            sm.us.s9[row][kk] = v.y;
        }
        __syncthreads();
        int i = tid >> 4, j = tid & 15;
        float acc = 0.f;
#pragma unroll 8
        for (int kk = 0; kk < 128; ++kk) {
            float d = sm.us.s8[i][kk] - sm.us.s9[j][kk];
            acc += d * d;
        }
        atomicAdd(&ws[US_OFF + i * 16 + j], acc);
    }

    __threadfence();
    grid.sync();
    __threadfence();

    // ---------------- phase 3: epilogue on block 0 ----------------
    if (blk == 0) {
        const float* PD2 = ws + PD_OFF;
        const float* US2 = ws + US_OFF;
        float sum_pos = 0.f, sum_om = 0.f, min_s2 = 3.4e38f;
#pragma unroll
        for (int q = 0; q < 4; ++q) {
            int pair = q * 256 + tid;
            int i = pair >> 5, j = pair & 31;
            int bi = i & 15, bj = j & 15;
            float pd = sqrtf(PD2[pair]);
            float us = sqrtf(US2[bi * 16 + bj]);
            float S = us - pd; S = S * S;
            float S2 = S * S;
            float ti0 = vs[bi * 3 + 0];
            float ti1 = sqrtf(vs[bi * 3 + 1] * vs[bi * 3 + 1] + vs[bi * 3 + 2] * vs[bi * 3 + 2]);
            float tj0 = vs[bj * 3 + 0];
            float tj1 = sqrtf(vs[bj * 3 + 1] * vs[bj * 3 + 1] + vs[bj * 3 + 2] * vs[bj * 3 + 2]);
            float prod = sqrtf(fabsf(ti0 * tj0) + fabsf(ti1 * tj1));
            float nvi = sqrtf(ti0 * ti0 + ti1 * ti1);
            float nvj = sqrtf(tj0 * tj0 + tj1 * tj1);
            float ss = prod / fmaxf(nvi, nvj);
            sum_pos += 0.5f * ss * S2;
            sum_om  += 1.0f - ss;
            min_s2 = fminf(min_s2, S2);
        }
        sum_pos = wave_sum(sum_pos);
        sum_om  = wave_sum(sum_om);
        min_s2  = wave_min(min_s2);
        int wid = tid >> 6, lane = tid & 63;
        if (lane == 0) { rp[wid] = sum_pos; ro[wid] = sum_om; rm[wid] = min_s2; }
        __syncthreads();
        if (tid == 0) {
            float SP = (rp[0] + rp[1]) + (rp[2] + rp[3]);
            float SO = (ro[0] + ro[1]) + (ro[2] + ro[3]);
            float SM = fminf(fminf(rm[0], rm[1]), fminf(rm[2], rm[3]));
            float scal = fmaxf(TAUC - SM, 0.0f);
            outp[0] = (SP + 0.5f * SO * scal) * (1.0f / 1024.0f) * (1.0f / 16.0f);
        }
    }
}

extern "C" void kernel_launch(void* const* d_in, const int* in_sizes, int n_in,
                              void* d_out, int out_size, void* d_ws, size_t ws_size,
                              hipStream_t stream) {
    const float* x1 = (const float*)d_in[0];
    const float* x2 = (const float*)d_in[1];
    const float* vs = (const float*)d_in[2];
    const float* u  = (const float*)d_in[3];
    const float* dt = (const float*)d_in[4];
    const float* dx = (const float*)d_in[5];
    float* ws  = (float*)d_ws;
    float* out = (float*)d_out;

    void* args[] = { (void*)&x1, (void*)&x2, (void*)&vs, (void*)&u,
                     (void*)&dt, (void*)&dx, (void*)&ws, (void*)&out };
    hipLaunchCooperativeKernel((void*)k_fused, dim3(256), dim3(256), args, 0, stream);
}

// Round 4
// 34.784 us; speedup vs baseline: 4.1757x; 4.1757x over previous
//
#include <hip/hip_runtime.h>

#define HW    16384   // 128*128
#define BD    16
#define TAUC  100.0f

// ws float layout:
//   pdPart : [0, 128*1024)            partial (y_i-a_j)^2 sums, [chunk(128)][pair(1024)]
//   usPart : [128*1024, +128*256)     partial (u8_i-u9_j)^2 sums, [chunk(128)][pair(256)]
#define PDP 0
#define USP (128*1024)

__device__ __forceinline__ float wave_sum(float v) {
    for (int off = 32; off > 0; off >>= 1) v += __shfl_down(v, off, 64);
    return v;
}
__device__ __forceinline__ float wave_min(float v) {
    for (int off = 32; off > 0; off >>= 1) v = fminf(v, __shfl_down(v, off, 64));
    return v;
}

// ---- K1: self-sufficient row blocks ----
// blocks 0..127  : PD row h=blk — gather rows h-1,h,h+1 of 32 planes, stencil->sY,
//                  32x32 pair partial sums over this row's 128 k-values.
// blocks 128..255: US row c=blk-128 — u[:,c,:,8/9], 16x16 pair partials.
__global__ __launch_bounds__(256)
void k_main(const float* __restrict__ x1, const float* __restrict__ x2,
            const float* __restrict__ vs, const float* __restrict__ u,
            const float* __restrict__ dtp, const float* __restrict__ dxp,
            float* __restrict__ ws)
{
    __shared__ float sA[32][132];
    __shared__ float sY[32][132];
    __shared__ float sc0[16], scx[16], scy[16], sdt[16];
    int tid = threadIdx.x, blk = blockIdx.x;

    if (blk < 128) {
        int h = blk;
        if (tid < 16) {
            sc0[tid] = vs[tid * 3 + 0];
            scx[tid] = vs[tid * 3 + 1];
            scy[tid] = vs[tid * 3 + 2];
            sdt[tid] = dtp[tid];
        }
        float dxv = dxp[0];
        float inv_dx = 1.0f / dxv, inv_dx2 = inv_dx * inv_dx;
        __syncthreads();
        int hm = (h + 127) & 127, hp = (h + 1) & 127;
#pragma unroll
        for (int s = 0; s < 16; ++s) {
            int e = s * 256 + tid;            // 0..4095 = plane*128 + w
            int p = e >> 7, w = e & 127;
            int b = p & 15;
            const float* plane = ((p < 16) ? x2 : x1) + (size_t)b * (HW * 10);
            int wm = (w + 127) & 127, wp = (w + 1) & 127;
            float c   = plane[(size_t)(h  * 128 + w ) * 10];
            float aw1 = plane[(size_t)(h  * 128 + wp) * 10];
            float awm = plane[(size_t)(h  * 128 + wm) * 10];
            float ah1 = plane[(size_t)(hp * 128 + w ) * 10];
            float ahm = plane[(size_t)(hm * 128 + w ) * 10];
            float lap = aw1 + awm + ah1 + ahm - 4.0f * c;
            float cx = scx[b], cy = scy[b];
            float xt = (cx <= 0.0f) ? (-cx * (c - aw1)) : (cx * (c - awm));
            float yt = (cy >= 0.0f) ? ( cy * (c - ahm)) : (-cy * (c - ah1));
            sA[p][w] = c;
            sY[p][w] = c - sdt[b] * (c * (xt + yt)) * inv_dx + sc0[b] * lap * inv_dx2;
        }
        __syncthreads();
        int ti = tid >> 4, tj = tid & 15;
        float a00 = 0.f, a01 = 0.f, a10 = 0.f, a11 = 0.f;
#pragma unroll 8
        for (int k = 0; k < 128; k += 4) {
            float4 y0 = *(const float4*)&sY[ti][k];
            float4 y1 = *(const float4*)&sY[ti + 16][k];
            float4 b0 = *(const float4*)&sA[tj][k];
            float4 b1 = *(const float4*)&sA[tj + 16][k];
            float d;
            d = y0.x - b0.x; a00 += d * d; d = y0.y - b0.y; a00 += d * d;
            d = y0.z - b0.z; a00 += d * d; d = y0.w - b0.w; a00 += d * d;
            d = y0.x - b1.x; a01 += d * d; d = y0.y - b1.y; a01 += d * d;
            d = y0.z - b1.z; a01 += d * d; d = y0.w - b1.w; a01 += d * d;
            d = y1.x - b0.x; a10 += d * d; d = y1.y - b0.y; a10 += d * d;
            d = y1.z - b0.z; a10 += d * d; d = y1.w - b0.w; a10 += d * d;
            d = y1.x - b1.x; a11 += d * d; d = y1.y - b1.y; a11 += d * d;
            d = y1.z - b1.z; a11 += d * d; d = y1.w - b1.w; a11 += d * d;
        }
        float* P = ws + PDP + blk * 1024;
        P[ ti       * 32 + tj     ] = a00;
        P[ ti       * 32 + tj + 16] = a01;
        P[(ti + 16) * 32 + tj     ] = a10;
        P[(ti + 16) * 32 + tj + 16] = a11;
    } else {
        int c = blk - 128;
        float (*s8)[132] = sA;
        float (*s9)[132] = sY;
#pragma unroll
        for (int s = 0; s < 8; ++s) {
            int e = s * 256 + tid;            // 0..2047 = plane*128 + w
            int p = e >> 7, w = e & 127;
            float2 v = *(const float2*)(u + (size_t)((p * 128 + c) * 128 + w) * 10 + 8);
            s8[p][w] = v.x;
            s9[p][w] = v.y;
        }
        __syncthreads();
        int i = tid >> 4, j = tid & 15;
        float acc = 0.f;
#pragma unroll 8
        for (int k = 0; k < 128; k += 4) {
            float4 a = *(const float4*)&s8[i][k];
            float4 b = *(const float4*)&s9[j][k];
            float d;
            d = a.x - b.x; acc += d * d; d = a.y - b.y; acc += d * d;
            d = a.z - b.z; acc += d * d; d = a.w - b.w; acc += d * d;
        }
        ws[USP + c * 256 + i * 16 + j] = acc;
    }
}

// ---- K2: fold partials + scalar epilogue (1 block, 1024 threads) ----
__global__ __launch_bounds__(1024)
void k_fin(const float* __restrict__ ws, const float* __restrict__ vs,
           float* __restrict__ outp)
{
    int tid = threadIdx.x;                    // pair id 0..1023
    __shared__ float sUS[256];
    __shared__ float rp[16], ro[16], rm[16];
    if (tid < 256) {
        float s = 0.f;
#pragma unroll 8
        for (int b = 0; b < 128; ++b) s += ws[USP + b * 256 + tid];
        sUS[tid] = s;
    }
    float pd2 = 0.f;
#pragma unroll 8
    for (int b = 0; b < 128; ++b) pd2 += ws[PDP + b * 1024 + tid];
    __syncthreads();
    int i = tid >> 5, j = tid & 31;
    int bi = i & 15, bj = j & 15;
    float pd = sqrtf(pd2);
    float us = sqrtf(sUS[bi * 16 + bj]);
    float S = us - pd; S = S * S;
    float S2 = S * S;
    float ti0 = vs[bi * 3 + 0];
    float ti1 = sqrtf(vs[bi * 3 + 1] * vs[bi * 3 + 1] + vs[bi * 3 + 2] * vs[bi * 3 + 2]);
    float tj0 = vs[bj * 3 + 0];
    float tj1 = sqrtf(vs[bj * 3 + 1] * vs[bj * 3 + 1] + vs[bj * 3 + 2] * vs[bj * 3 + 2]);
    float prod = sqrtf(fabsf(ti0 * tj0) + fabsf(ti1 * tj1));
    float nvi = sqrtf(ti0 * ti0 + ti1 * ti1);
    float nvj = sqrtf(tj0 * tj0 + tj1 * tj1);
    float ss = prod / fmaxf(nvi, nvj);
    float pos = 0.5f * ss * S2;
    float om  = 1.0f - ss;
    float sp = wave_sum(pos), so = wave_sum(om), sm = wave_min(S2);
    int wid = tid >> 6, lane = tid & 63;
    if (lane == 0) { rp[wid] = sp; ro[wid] = so; rm[wid] = sm; }
    __syncthreads();
    if (tid == 0) {
        float SP = 0.f, SO = 0.f, SM = rm[0];
        for (int k = 0; k < 16; ++k) { SP += rp[k]; SO += ro[k]; SM = fminf(SM, rm[k]); }
        float scal = fmaxf(TAUC - SM, 0.0f);
        outp[0] = (SP + 0.5f * SO * scal) * (1.0f / 1024.0f) * (1.0f / 16.0f);
    }
}

extern "C" void kernel_launch(void* const* d_in, const int* in_sizes, int n_in,
                              void* d_out, int out_size, void* d_ws, size_t ws_size,
                              hipStream_t stream) {
    const float* x1 = (const float*)d_in[0];
    const float* x2 = (const float*)d_in[1];
    const float* vs = (const float*)d_in[2];
    const float* u  = (const float*)d_in[3];
    const float* dt = (const float*)d_in[4];
    const float* dx = (const float*)d_in[5];
    float* ws  = (float*)d_ws;
    float* out = (float*)d_out;

    k_main<<<256, 256, 0, stream>>>(x1, x2, vs, u, dt, dx, ws);
    k_fin <<<1,  1024, 0, stream>>>(ws, vs, out);
}